// Round 1
// baseline (789.824 us; speedup 1.0000x reference)
//
#include <hip/hip_runtime.h>

#define D 128
#define ROWS_PER_BLOCK 32

// C = act(X @ W + b). One block: 256 threads, 32-row tile.
// Thread layout: cg = t&31 -> cols 4*cg..4*cg+3 ; rg = t>>5 -> rows rg+8*ri (ri=0..3).
// W (64KB) + x tile (16KB) in LDS -> 2 blocks/CU. Each W LDS read is reused
// across 4 rows -> ~64 FMA per 8 LDS b128 reads -> compute-bound.
template <bool RELU>
__global__ __launch_bounds__(256) void gemm_bias_act(
    const float* xin, const float* __restrict__ W,
    const float* __restrict__ b, float* xout, int n_rows)
{
    __shared__ float Ws[D * D];
    __shared__ float xs[ROWS_PER_BLOCK * D];

    const int t = threadIdx.x;
    const int row0 = blockIdx.x * ROWS_PER_BLOCK;

    // Load W into LDS (4096 float4, 16 per thread), coalesced.
    const float4* Wv = (const float4*)W;
    float4* Wsv = (float4*)Ws;
#pragma unroll
    for (int i = 0; i < 16; ++i) Wsv[t + 256 * i] = Wv[t + 256 * i];

    // Load 32-row x tile (1024 float4, 4 per thread), coalesced, guarded.
    const float4* xv = (const float4*)xin;
    float4* xsv = (float4*)xs;
#pragma unroll
    for (int i = 0; i < 4; ++i) {
        int f4 = t + 256 * i;                 // float4 index within tile
        int row = row0 + (f4 >> 5);           // 32 float4 per row
        if (row < n_rows) xsv[f4] = xv[(size_t)row0 * 32 + f4];
    }
    __syncthreads();

    const int cg = t & 31;
    const int rg = t >> 5;
    float4 bias = ((const float4*)b)[cg];

    float4 acc[4];
#pragma unroll
    for (int ri = 0; ri < 4; ++ri) acc[ri] = make_float4(0.f, 0.f, 0.f, 0.f);

#pragma unroll 4
    for (int k = 0; k < D; k += 4) {
        float4 w0 = Wsv[(k + 0) * 32 + cg];
        float4 w1 = Wsv[(k + 1) * 32 + cg];
        float4 w2 = Wsv[(k + 2) * 32 + cg];
        float4 w3 = Wsv[(k + 3) * 32 + cg];
#pragma unroll
        for (int ri = 0; ri < 4; ++ri) {
            float4 xa = xsv[(rg + 8 * ri) * 32 + (k >> 2)];
            acc[ri].x = fmaf(xa.x, w0.x, fmaf(xa.y, w1.x, fmaf(xa.z, w2.x, fmaf(xa.w, w3.x, acc[ri].x))));
            acc[ri].y = fmaf(xa.x, w0.y, fmaf(xa.y, w1.y, fmaf(xa.z, w2.y, fmaf(xa.w, w3.y, acc[ri].y))));
            acc[ri].z = fmaf(xa.x, w0.z, fmaf(xa.y, w1.z, fmaf(xa.z, w2.z, fmaf(xa.w, w3.z, acc[ri].z))));
            acc[ri].w = fmaf(xa.x, w0.w, fmaf(xa.y, w1.w, fmaf(xa.z, w2.w, fmaf(xa.w, w3.w, acc[ri].w))));
        }
    }

    // In-place safety (GEMM2: xin == xout): the whole tile was staged to LDS
    // before this point and rows are partitioned across blocks.
#pragma unroll
    for (int ri = 0; ri < 4; ++ri) {
        int r = rg + 8 * ri;
        int row = row0 + r;
        if (row >= n_rows) continue;
        float4 o;
        o.x = acc[ri].x + bias.x;
        o.y = acc[ri].y + bias.y;
        o.z = acc[ri].z + bias.z;
        o.w = acc[ri].w + bias.w;
        if (RELU) {
            o.x = fmaxf(o.x, 0.f);
            o.y = fmaxf(o.y, 0.f);
            o.z = fmaxf(o.z, 0.f);
            o.w = fmaxf(o.w, 0.f);
        }
        ((float4*)xout)[(size_t)row * 32 + cg] = o;
    }
}

__global__ __launch_bounds__(256) void zero_kernel(float4* p, int n4)
{
    int i = blockIdx.x * 256 + threadIdx.x;
    int stride = gridDim.x * 256;
    for (; i < n4; i += stride) p[i] = make_float4(0.f, 0.f, 0.f, 0.f);
}

// One thread per (edge, col): agg[dst][c] += h[src][c].
__global__ __launch_bounds__(256) void scatter_kernel(
    const float* __restrict__ h, const int* __restrict__ esrc,
    const int* __restrict__ edst, float* __restrict__ agg, int n_items)
{
    int idx = blockIdx.x * 256 + threadIdx.x;
    int stride = gridDim.x * 256;
    for (; idx < n_items; idx += stride) {
        int e = idx >> 7;
        int c = idx & 127;
        int s = esrc[e];
        int d = edst[e];
        float v = h[(size_t)s * D + c];
        unsafeAtomicAdd(&agg[(size_t)d * D + c], v);
    }
}

extern "C" void kernel_launch(void* const* d_in, const int* in_sizes, int n_in,
                              void* d_out, int out_size, void* d_ws, size_t ws_size,
                              hipStream_t stream)
{
    const float* x    = (const float*)d_in[0];
    const int*   esrc = (const int*)d_in[1];
    const int*   edst = (const int*)d_in[2];
    const float* W1   = (const float*)d_in[3];
    const float* b1   = (const float*)d_in[4];
    const float* W2   = (const float*)d_in[5];
    const float* b2   = (const float*)d_in[6];
    float* out = (float*)d_out;
    float* h   = (float*)d_ws;

    const int N = in_sizes[0] / D;   // 100000 nodes
    const int E = in_sizes[1];       // 1600000 edges

    const int nblk = (N + ROWS_PER_BLOCK - 1) / ROWS_PER_BLOCK;  // 3125

    // 1) h = relu(x @ W1 + b1)
    gemm_bias_act<true><<<nblk, 256, 0, stream>>>(x, W1, b1, h, N);

    // 2) agg (in d_out) = 0
    zero_kernel<<<2048, 256, 0, stream>>>((float4*)out, N * D / 4);

    // 3) agg[dst] += h[src] over edges
    scatter_kernel<<<8192, 256, 0, stream>>>(h, esrc, edst, out, E * D);

    // 4) out = agg @ W2 + b2 (in place)
    gemm_bias_act<false><<<nblk, 256, 0, stream>>>(out, W2, b2, out, N);
}

// Round 2
// 518.207 us; speedup vs baseline: 1.5241x; 1.5241x over previous
//
#include <hip/hip_runtime.h>

#define D 128
#define ROWS_PER_BLOCK 32
#define SLOT_CAP 64
#define OVF_CAP 4096

// ---------------- GEMM: C = act(X @ W + b) ----------------
// One block: 256 threads, 32-row tile. W (64KB) + x tile (16KB) in LDS.
template <bool RELU>
__global__ __launch_bounds__(256) void gemm_bias_act(
    const float* xin, const float* __restrict__ W,
    const float* __restrict__ b, float* xout, int n_rows)
{
    __shared__ float Ws[D * D];
    __shared__ float xs[ROWS_PER_BLOCK * D];

    const int t = threadIdx.x;
    const int row0 = blockIdx.x * ROWS_PER_BLOCK;

    const float4* Wv = (const float4*)W;
    float4* Wsv = (float4*)Ws;
#pragma unroll
    for (int i = 0; i < 16; ++i) Wsv[t + 256 * i] = Wv[t + 256 * i];

    const float4* xv = (const float4*)xin;
    float4* xsv = (float4*)xs;
#pragma unroll
    for (int i = 0; i < 4; ++i) {
        int f4 = t + 256 * i;
        int row = row0 + (f4 >> 5);
        if (row < n_rows) xsv[f4] = xv[(size_t)row0 * 32 + f4];
    }
    __syncthreads();

    const int cg = t & 31;
    const int rg = t >> 5;
    float4 bias = ((const float4*)b)[cg];

    float4 acc[4];
#pragma unroll
    for (int ri = 0; ri < 4; ++ri) acc[ri] = make_float4(0.f, 0.f, 0.f, 0.f);

#pragma unroll 4
    for (int k = 0; k < D; k += 4) {
        float4 w0 = Wsv[(k + 0) * 32 + cg];
        float4 w1 = Wsv[(k + 1) * 32 + cg];
        float4 w2 = Wsv[(k + 2) * 32 + cg];
        float4 w3 = Wsv[(k + 3) * 32 + cg];
#pragma unroll
        for (int ri = 0; ri < 4; ++ri) {
            float4 xa = xsv[(rg + 8 * ri) * 32 + (k >> 2)];
            acc[ri].x = fmaf(xa.x, w0.x, fmaf(xa.y, w1.x, fmaf(xa.z, w2.x, fmaf(xa.w, w3.x, acc[ri].x))));
            acc[ri].y = fmaf(xa.x, w0.y, fmaf(xa.y, w1.y, fmaf(xa.z, w2.y, fmaf(xa.w, w3.y, acc[ri].y))));
            acc[ri].z = fmaf(xa.x, w0.z, fmaf(xa.y, w1.z, fmaf(xa.z, w2.z, fmaf(xa.w, w3.z, acc[ri].z))));
            acc[ri].w = fmaf(xa.x, w0.w, fmaf(xa.y, w1.w, fmaf(xa.z, w2.w, fmaf(xa.w, w3.w, acc[ri].w))));
        }
    }

#pragma unroll
    for (int ri = 0; ri < 4; ++ri) {
        int r = rg + 8 * ri;
        int row = row0 + r;
        if (row >= n_rows) continue;
        float4 o;
        o.x = acc[ri].x + bias.x;
        o.y = acc[ri].y + bias.y;
        o.z = acc[ri].z + bias.z;
        o.w = acc[ri].w + bias.w;
        if (RELU) {
            o.x = fmaxf(o.x, 0.f);
            o.y = fmaxf(o.y, 0.f);
            o.z = fmaxf(o.z, 0.f);
            o.w = fmaxf(o.w, 0.f);
        }
        ((float4*)xout)[(size_t)row * 32 + cg] = o;
    }
}

// ---------------- CSR-by-dst build (capacity slots) ----------------
__global__ __launch_bounds__(256) void fill_kernel(
    const int* __restrict__ esrc, const int* __restrict__ edst,
    int* __restrict__ cnt, int* __restrict__ slots,
    int* __restrict__ ovf_cnt, int2* __restrict__ ovf_list, int E)
{
    int e = blockIdx.x * 256 + threadIdx.x;
    if (e >= E) return;
    int s = esrc[e];
    int d = edst[e];
    int pos = atomicAdd(&cnt[d], 1);
    if (pos < SLOT_CAP) {
        slots[(size_t)d * SLOT_CAP + pos] = s;
    } else {
        int o = atomicAdd(ovf_cnt, 1);
        if (o < OVF_CAP) ovf_list[o] = make_int2(s, d);
    }
}

// ---------------- pull: agg[n] = sum over slots of h[src] ----------------
// 128 threads per node (thread t -> col t), 2 nodes per 256-thread block.
__global__ __launch_bounds__(256) void pull_kernel(
    const float* __restrict__ h, const int* __restrict__ slots,
    const int* __restrict__ cnt, float* __restrict__ agg, int n_nodes)
{
    int node = blockIdx.x * 2 + (threadIdx.x >> 7);
    int c = threadIdx.x & 127;
    if (node >= n_nodes) return;
    int deg = cnt[node];
    if (deg > SLOT_CAP) deg = SLOT_CAP;
    const int* sl = slots + (size_t)node * SLOT_CAP;
    float acc = 0.f;
    for (int i = 0; i < deg; ++i) {
        int s = sl[i];                       // same addr across group -> broadcast
        acc += h[(size_t)s * D + c];         // 512B row gather, coalesced
    }
    agg[(size_t)node * D + c] = acc;
}

// Apply rare overflow edges with f32 atomics (normally count == 0).
__global__ __launch_bounds__(128) void ovf_kernel(
    const float* __restrict__ h, const int* __restrict__ ovf_cnt,
    const int2* __restrict__ ovf_list, float* __restrict__ agg)
{
    int n = *ovf_cnt;
    if (n > OVF_CAP) n = OVF_CAP;
    int c = threadIdx.x;  // 128 cols
    for (int i = blockIdx.x; i < n; i += gridDim.x) {
        int2 sd = ovf_list[i];
        unsafeAtomicAdd(&agg[(size_t)sd.y * D + c], h[(size_t)sd.x * D + c]);
    }
}

// ---------------- fallback (atomic scatter) ----------------
__global__ __launch_bounds__(256) void zero_kernel(float4* p, int n4)
{
    int i = blockIdx.x * 256 + threadIdx.x;
    int stride = gridDim.x * 256;
    for (; i < n4; i += stride) p[i] = make_float4(0.f, 0.f, 0.f, 0.f);
}

__global__ __launch_bounds__(256) void scatter_kernel(
    const float* __restrict__ h, const int* __restrict__ esrc,
    const int* __restrict__ edst, float* __restrict__ agg, int n_items)
{
    int idx = blockIdx.x * 256 + threadIdx.x;
    int stride = gridDim.x * 256;
    for (; idx < n_items; idx += stride) {
        int e = idx >> 7;
        int c = idx & 127;
        int s = esrc[e];
        int d = edst[e];
        float v = h[(size_t)s * D + c];
        unsafeAtomicAdd(&agg[(size_t)d * D + c], v);
    }
}

extern "C" void kernel_launch(void* const* d_in, const int* in_sizes, int n_in,
                              void* d_out, int out_size, void* d_ws, size_t ws_size,
                              hipStream_t stream)
{
    const float* x    = (const float*)d_in[0];
    const int*   esrc = (const int*)d_in[1];
    const int*   edst = (const int*)d_in[2];
    const float* W1   = (const float*)d_in[3];
    const float* b1   = (const float*)d_in[4];
    const float* W2   = (const float*)d_in[5];
    const float* b2   = (const float*)d_in[6];
    float* out = (float*)d_out;

    const int N = in_sizes[0] / D;   // 100000
    const int E = in_sizes[1];       // 1600000

    // Workspace layout
    char* ws = (char*)d_ws;
    size_t off_h     = 0;
    size_t off_slots = off_h + (size_t)N * D * 4;                 // 51.2 MB
    size_t off_cnt   = off_slots + (size_t)N * SLOT_CAP * 4;      // +25.6 MB
    size_t off_ovfc  = off_cnt + (size_t)N * 4;                   // +0.4 MB
    size_t off_ovfl  = (off_ovfc + 15) & ~(size_t)15;
    size_t need      = off_ovfl + 16 + (size_t)OVF_CAP * 8;

    float* h = (float*)(ws + off_h);
    const int nblk = (N + ROWS_PER_BLOCK - 1) / ROWS_PER_BLOCK;

    // 1) h = relu(x @ W1 + b1)
    gemm_bias_act<true><<<nblk, 256, 0, stream>>>(x, W1, b1, h, N);

    if (ws_size >= need) {
        int*  cnt      = (int*)(ws + off_cnt);
        int*  slots    = (int*)(ws + off_slots);
        int*  ovf_cnt  = (int*)(ws + off_ovfl);          // first 4B of 16B pad
        int2* ovf_list = (int2*)(ws + off_ovfl + 16);

        hipMemsetAsync(cnt, 0, (size_t)N * 4, stream);
        hipMemsetAsync(ovf_cnt, 0, 16, stream);

        // 2) slot fill: one int atomic per edge
        fill_kernel<<<(E + 255) / 256, 256, 0, stream>>>(
            esrc, edst, cnt, slots, ovf_cnt, ovf_list, E);

        // 3) pull-sum into out (written exactly once per element)
        pull_kernel<<<(N + 1) / 2, 256, 0, stream>>>(h, slots, cnt, out, N);

        // 4) rare overflow edges
        ovf_kernel<<<32, 128, 0, stream>>>(h, ovf_cnt, ovf_list, out);
    } else {
        // Fallback: atomic scatter (round-1 path)
        zero_kernel<<<2048, 256, 0, stream>>>((float4*)out, N * D / 4);
        scatter_kernel<<<8192, 256, 0, stream>>>(h, esrc, edst, out, (size_t)E * D);
    }

    // 5) out = agg @ W2 + b2 (in place)
    gemm_bias_act<false><<<nblk, 256, 0, stream>>>(out, W2, b2, out, N);
}

// Round 3
// 226.639 us; speedup vs baseline: 3.4849x; 2.2865x over previous
//
#include <hip/hip_runtime.h>

#define D 128
#define SLOT_CAP 64
#define OVF_CAP 4096

typedef __attribute__((ext_vector_type(8))) short short8x;
typedef __attribute__((ext_vector_type(4))) float f32x4;

// ---- bf16 helpers (manual RNE, no header variance) ----
__device__ inline unsigned int f2bf(float f) {
    unsigned int u = __builtin_bit_cast(unsigned int, f);
    return (u + 0x7fffu + ((u >> 16) & 1u)) >> 16;
}
__device__ inline float bflo(unsigned int v) {   // low 16 bits
    return __builtin_bit_cast(float, v << 16);
}
__device__ inline float bfhi(unsigned int v) {   // high 16 bits
    return __builtin_bit_cast(float, v & 0xffff0000u);
}
__device__ inline unsigned int pack2(float lo, float hi) {
    return f2bf(lo) | (f2bf(hi) << 16);
}

// ================= W pre-pack: lane-linear B fragments =================
// frag f = kt*8+nt; lane l provides B[k0+(l>>4)*8+j][n0+(l&15)], j=0..7.
// Stored at pack[(widx*2048) + f*64 + l] as uint4 (8 bf16).
__global__ __launch_bounds__(256) void pack_w(
    const float* __restrict__ W1, const float* __restrict__ W2,
    uint4* __restrict__ pack)
{
    int e = blockIdx.x * 256 + threadIdx.x;      // 0..4095
    const float* W = (e & 2048) ? W2 : W1;
    int f = (e >> 6) & 31, l = e & 63;
    int kt = f >> 3, nt = f & 7;
    int k0 = kt * 32 + (l >> 4) * 8;
    int col = nt * 16 + (l & 15);
    unsigned int v[8];
#pragma unroll
    for (int j = 0; j < 8; ++j) v[j] = f2bf(W[(size_t)(k0 + j) * D + col]);
    uint4 o;
    o.x = v[0] | (v[1] << 16);
    o.y = v[2] | (v[3] << 16);
    o.z = v[4] | (v[5] << 16);
    o.w = v[6] | (v[7] << 16);
    pack[e] = o;
}

// ================= MFMA GEMM: out = act(X @ W + b) =================
// Block: 256 thr = 4 waves, 128 rows (wave w -> rows w*32..w*32+31).
// LDS: x tile 32KB (XOR-swizzled 16B chunks), packed W frags 32KB.
template <bool IN_BF16, bool RELU, bool OUT_BF16>
__global__ __launch_bounds__(256) void gemm_mfma(
    const void* __restrict__ xin, const uint4* __restrict__ wpack,
    const float* __restrict__ b, void* __restrict__ xout, int n_rows)
{
    __shared__ uint4 xs4[2048];
    __shared__ uint4 ws4[2048];
    const int t = threadIdx.x;
    const int row0 = blockIdx.x * 128;

#pragma unroll
    for (int i = 0; i < 8; ++i) ws4[t + 256 * i] = wpack[t + 256 * i];

    if (IN_BF16) {
        const uint4* g = (const uint4*)xin;
#pragma unroll
        for (int i = 0; i < 8; ++i) {
            int c = t + 256 * i;
            int row = c >> 4, kc = c & 15;
            int grow = row0 + row;
            if (grow < n_rows)
                xs4[row * 16 + (kc ^ (row & 7))] = g[(size_t)grow * 16 + kc];
        }
    } else {
        const float4* g = (const float4*)xin;
#pragma unroll
        for (int i = 0; i < 8; ++i) {
            int c = t + 256 * i;
            int row = c >> 4, kc = c & 15;
            int grow = row0 + row;
            if (grow < n_rows) {
                float4 f0 = g[(size_t)grow * 32 + kc * 2];
                float4 f1 = g[(size_t)grow * 32 + kc * 2 + 1];
                uint4 v;
                v.x = pack2(f0.x, f0.y);
                v.y = pack2(f0.z, f0.w);
                v.z = pack2(f1.x, f1.y);
                v.w = pack2(f1.z, f1.w);
                xs4[row * 16 + (kc ^ (row & 7))] = v;
            }
        }
    }
    __syncthreads();

    const int l = t & 63;
    const int w = t >> 6;
    const int l15 = l & 15;
    const int lk = l >> 4;

    float bias_v[8];
#pragma unroll
    for (int nt = 0; nt < 8; ++nt) bias_v[nt] = b[nt * 16 + l15];

    f32x4 acc[2][8];
#pragma unroll
    for (int rt = 0; rt < 2; ++rt)
#pragma unroll
        for (int nt = 0; nt < 8; ++nt) acc[rt][nt] = (f32x4){0.f, 0.f, 0.f, 0.f};

    const int arow0 = w * 32 + l15;
    const int arow1 = arow0 + 16;

#pragma unroll
    for (int kt = 0; kt < 4; ++kt) {
        int kc0 = kt * 4 + lk;
        short8x a0 = *(const short8x*)&xs4[arow0 * 16 + (kc0 ^ (arow0 & 7))];
        short8x a1 = *(const short8x*)&xs4[arow1 * 16 + (kc0 ^ (arow1 & 7))];
#pragma unroll
        for (int nt = 0; nt < 8; ++nt) {
            short8x bf = *(const short8x*)&ws4[(kt * 8 + nt) * 64 + l];
            acc[0][nt] = __builtin_amdgcn_mfma_f32_16x16x32_bf16(a0, bf, acc[0][nt], 0, 0, 0);
            acc[1][nt] = __builtin_amdgcn_mfma_f32_16x16x32_bf16(a1, bf, acc[1][nt], 0, 0, 0);
        }
    }

    // D layout: col = l&15, row = (l>>4)*4 + reg   [m89-verified]
#pragma unroll
    for (int rt = 0; rt < 2; ++rt) {
#pragma unroll
        for (int r = 0; r < 4; ++r) {
            int row = row0 + w * 32 + rt * 16 + lk * 4 + r;
            if (row >= n_rows) continue;
#pragma unroll
            for (int nt = 0; nt < 8; ++nt) {
                float v = acc[rt][nt][r] + bias_v[nt];
                if (RELU) v = fmaxf(v, 0.f);
                int col = nt * 16 + l15;
                if (OUT_BF16)
                    ((unsigned short*)xout)[(size_t)row * D + col] = (unsigned short)f2bf(v);
                else
                    ((float*)xout)[(size_t)row * D + col] = v;
            }
        }
    }
}

// ================= CSR-by-dst build =================
__global__ __launch_bounds__(256) void fill_kernel(
    const int* __restrict__ esrc, const int* __restrict__ edst,
    int* __restrict__ cnt, int* __restrict__ slots,
    int* __restrict__ ovf_cnt, int2* __restrict__ ovf_list, int E)
{
    int e = blockIdx.x * 256 + threadIdx.x;
    if (e >= E) return;
    int s = esrc[e];
    int d = edst[e];
    int pos = atomicAdd(&cnt[d], 1);
    if (pos < SLOT_CAP) {
        slots[(size_t)d * SLOT_CAP + pos] = s;
    } else {
        int o = atomicAdd(ovf_cnt, 1);
        if (o < OVF_CAP) ovf_list[o] = make_int2(s, d);
    }
}

// ================= pull (bf16 rows): agg[n] = sum h[src] =================
// 32 lanes per node (lane -> 4 cols via uint2), 8 nodes per 256-thr block.
__global__ __launch_bounds__(256) void pull_bf16(
    const uint2* __restrict__ h2, const int* __restrict__ slots,
    const int* __restrict__ cnt, uint2* __restrict__ agg2, int n_nodes)
{
    int node = blockIdx.x * 8 + (threadIdx.x >> 5);
    int lane = threadIdx.x & 31;
    if (node >= n_nodes) return;
    int deg = cnt[node];
    if (deg > SLOT_CAP) deg = SLOT_CAP;
    const int* sl = slots + (size_t)node * SLOT_CAP;

    float a0 = 0.f, a1 = 0.f, a2 = 0.f, a3 = 0.f;
    int i = 0;
    for (; i + 4 <= deg; i += 4) {
        int4 s = *(const int4*)(sl + i);
        uint2 v0 = h2[(size_t)s.x * 32 + lane];
        uint2 v1 = h2[(size_t)s.y * 32 + lane];
        uint2 v2 = h2[(size_t)s.z * 32 + lane];
        uint2 v3 = h2[(size_t)s.w * 32 + lane];
        a0 += bflo(v0.x) + bflo(v1.x) + bflo(v2.x) + bflo(v3.x);
        a1 += bfhi(v0.x) + bfhi(v1.x) + bfhi(v2.x) + bfhi(v3.x);
        a2 += bflo(v0.y) + bflo(v1.y) + bflo(v2.y) + bflo(v3.y);
        a3 += bfhi(v0.y) + bfhi(v1.y) + bfhi(v2.y) + bfhi(v3.y);
    }
    for (; i < deg; ++i) {
        int s = sl[i];
        uint2 v = h2[(size_t)s * 32 + lane];
        a0 += bflo(v.x); a1 += bfhi(v.x);
        a2 += bflo(v.y); a3 += bfhi(v.y);
    }
    agg2[(size_t)node * 32 + lane] = make_uint2(pack2(a0, a1), pack2(a2, a3));
}

// Rare overflow edges: ONE block, serial over edges, no races (lane owns cols).
__global__ __launch_bounds__(32) void ovf_bf16(
    const int* __restrict__ ovf_cnt, const int2* __restrict__ ovf_list,
    const uint2* __restrict__ h2, uint2* __restrict__ agg2)
{
    int n = *ovf_cnt;
    if (n > OVF_CAP) n = OVF_CAP;
    int lane = threadIdx.x;  // 32
    for (int i = 0; i < n; ++i) {
        int2 sd = ovf_list[i];
        uint2 hv = h2[(size_t)sd.x * 32 + lane];
        uint2 av = agg2[(size_t)sd.y * 32 + lane];
        float a0 = bflo(av.x) + bflo(hv.x);
        float a1 = bfhi(av.x) + bfhi(hv.x);
        float a2 = bflo(av.y) + bflo(hv.y);
        float a3 = bfhi(av.y) + bfhi(hv.y);
        agg2[(size_t)sd.y * 32 + lane] = make_uint2(pack2(a0, a1), pack2(a2, a3));
    }
}

// ================= fallback path (round-1, f32 atomics) =================
template <bool RELU>
__global__ __launch_bounds__(256) void gemm_bias_act(
    const float* xin, const float* __restrict__ W,
    const float* __restrict__ b, float* xout, int n_rows)
{
    __shared__ float Ws[D * D];
    __shared__ float xs[32 * D];
    const int t = threadIdx.x;
    const int row0 = blockIdx.x * 32;
    const float4* Wv = (const float4*)W;
    float4* Wsv = (float4*)Ws;
#pragma unroll
    for (int i = 0; i < 16; ++i) Wsv[t + 256 * i] = Wv[t + 256 * i];
    const float4* xv = (const float4*)xin;
    float4* xsv = (float4*)xs;
#pragma unroll
    for (int i = 0; i < 4; ++i) {
        int f4 = t + 256 * i;
        int row = row0 + (f4 >> 5);
        if (row < n_rows) xsv[f4] = xv[(size_t)row0 * 32 + f4];
    }
    __syncthreads();
    const int cg = t & 31;
    const int rg = t >> 5;
    float4 bias = ((const float4*)b)[cg];
    float4 acc[4];
#pragma unroll
    for (int ri = 0; ri < 4; ++ri) acc[ri] = make_float4(0.f, 0.f, 0.f, 0.f);
#pragma unroll 4
    for (int k = 0; k < D; k += 4) {
        float4 w0 = Wsv[(k + 0) * 32 + cg];
        float4 w1 = Wsv[(k + 1) * 32 + cg];
        float4 w2 = Wsv[(k + 2) * 32 + cg];
        float4 w3 = Wsv[(k + 3) * 32 + cg];
#pragma unroll
        for (int ri = 0; ri < 4; ++ri) {
            float4 xa = xsv[(rg + 8 * ri) * 32 + (k >> 2)];
            acc[ri].x = fmaf(xa.x, w0.x, fmaf(xa.y, w1.x, fmaf(xa.z, w2.x, fmaf(xa.w, w3.x, acc[ri].x))));
            acc[ri].y = fmaf(xa.x, w0.y, fmaf(xa.y, w1.y, fmaf(xa.z, w2.y, fmaf(xa.w, w3.y, acc[ri].y))));
            acc[ri].z = fmaf(xa.x, w0.z, fmaf(xa.y, w1.z, fmaf(xa.z, w2.z, fmaf(xa.w, w3.z, acc[ri].z))));
            acc[ri].w = fmaf(xa.x, w0.w, fmaf(xa.y, w1.w, fmaf(xa.z, w2.w, fmaf(xa.w, w3.w, acc[ri].w))));
        }
    }
#pragma unroll
    for (int ri = 0; ri < 4; ++ri) {
        int row = row0 + rg + 8 * ri;
        if (row >= n_rows) continue;
        float4 o;
        o.x = acc[ri].x + bias.x; o.y = acc[ri].y + bias.y;
        o.z = acc[ri].z + bias.z; o.w = acc[ri].w + bias.w;
        if (RELU) {
            o.x = fmaxf(o.x, 0.f); o.y = fmaxf(o.y, 0.f);
            o.z = fmaxf(o.z, 0.f); o.w = fmaxf(o.w, 0.f);
        }
        ((float4*)xout)[(size_t)row * 32 + cg] = o;
    }
}

__global__ __launch_bounds__(256) void zero_kernel(float4* p, int n4)
{
    int i = blockIdx.x * 256 + threadIdx.x;
    int stride = gridDim.x * 256;
    for (; i < n4; i += stride) p[i] = make_float4(0.f, 0.f, 0.f, 0.f);
}

__global__ __launch_bounds__(256) void scatter_kernel(
    const float* __restrict__ h, const int* __restrict__ esrc,
    const int* __restrict__ edst, float* __restrict__ agg, long n_items)
{
    long idx = (long)blockIdx.x * 256 + threadIdx.x;
    long stride = (long)gridDim.x * 256;
    for (; idx < n_items; idx += stride) {
        int e = (int)(idx >> 7);
        int c = (int)(idx & 127);
        int s = esrc[e];
        int d = edst[e];
        unsafeAtomicAdd(&agg[(size_t)d * D + c], h[(size_t)s * D + c]);
    }
}

extern "C" void kernel_launch(void* const* d_in, const int* in_sizes, int n_in,
                              void* d_out, int out_size, void* d_ws, size_t ws_size,
                              hipStream_t stream)
{
    const float* x    = (const float*)d_in[0];
    const int*   esrc = (const int*)d_in[1];
    const int*   edst = (const int*)d_in[2];
    const float* W1   = (const float*)d_in[3];
    const float* b1   = (const float*)d_in[4];
    const float* W2   = (const float*)d_in[5];
    const float* b2   = (const float*)d_in[6];
    float* out = (float*)d_out;

    const int N = in_sizes[0] / D;   // 100000
    const int E = in_sizes[1];       // 1600000

    char* ws = (char*)d_ws;
    size_t off_h     = 0;
    size_t off_agg   = off_h + (size_t)N * 256;
    size_t off_slots = off_agg + (size_t)N * 256;
    size_t off_cnt   = off_slots + (size_t)N * SLOT_CAP * 4;
    size_t off_pack  = (off_cnt + (size_t)N * 4 + 15) & ~(size_t)15;
    size_t off_ovfc  = off_pack + 65536;
    size_t off_ovfl  = off_ovfc + 16;
    size_t need      = off_ovfl + (size_t)OVF_CAP * 8;

    const int nblk = (N + 127) / 128;   // 782

    if (ws_size >= need) {
        uint2* h2       = (uint2*)(ws + off_h);
        uint2* agg2     = (uint2*)(ws + off_agg);
        int*   slots    = (int*)(ws + off_slots);
        int*   cnt      = (int*)(ws + off_cnt);
        uint4* pack     = (uint4*)(ws + off_pack);
        int*   ovf_cnt  = (int*)(ws + off_ovfc);
        int2*  ovf_list = (int2*)(ws + off_ovfl);

        hipMemsetAsync(cnt, 0, (size_t)N * 4, stream);
        hipMemsetAsync(ovf_cnt, 0, 16, stream);

        // 0) pack W1,W2 into lane-linear bf16 B-fragments
        pack_w<<<16, 256, 0, stream>>>(W1, W2, pack);

        // 1) h = relu(x @ W1 + b1), bf16 out
        gemm_mfma<false, true, true><<<nblk, 256, 0, stream>>>(x, pack, b1, h2, N);

        // 2) CSR slots
        fill_kernel<<<(E + 255) / 256, 256, 0, stream>>>(
            esrc, edst, cnt, slots, ovf_cnt, ovf_list, E);

        // 3) agg = pull-sum (bf16)
        pull_bf16<<<(N + 7) / 8, 256, 0, stream>>>(h2, slots, cnt, agg2, N);

        // 4) rare overflow edges (serial, normally 0)
        ovf_bf16<<<1, 32, 0, stream>>>(ovf_cnt, ovf_list, h2, agg2);

        // 5) out = agg @ W2 + b2, f32 out
        gemm_mfma<true, false, false><<<nblk, 256, 0, stream>>>(agg2, pack + 2048, b2, out, N);
    } else {
        float* h = (float*)ws;
        const int nb32 = (N + 31) / 32;
        gemm_bias_act<true><<<nb32, 256, 0, stream>>>(x, W1, b1, h, N);
        zero_kernel<<<2048, 256, 0, stream>>>((float4*)out, N * D / 4);
        scatter_kernel<<<8192, 256, 0, stream>>>(h, esrc, edst, out, (long)E * D);
        gemm_bias_act<false><<<nb32, 256, 0, stream>>>(out, W2, b2, out, N);
    }
}

// Round 4
// 225.791 us; speedup vs baseline: 3.4980x; 1.0038x over previous
//
#include <hip/hip_runtime.h>

#define D 128

typedef __attribute__((ext_vector_type(8))) short short8x;
typedef __attribute__((ext_vector_type(4))) float f32x4;

// ---- bf16 helpers (manual RNE) ----
__device__ inline unsigned int f2bf(float f) {
    unsigned int u = __builtin_bit_cast(unsigned int, f);
    return (u + 0x7fffu + ((u >> 16) & 1u)) >> 16;
}
__device__ inline float bflo(unsigned int v) {
    return __builtin_bit_cast(float, v << 16);
}
__device__ inline float bfhi(unsigned int v) {
    return __builtin_bit_cast(float, v & 0xffff0000u);
}
__device__ inline unsigned int pack2(float lo, float hi) {
    return f2bf(lo) | (f2bf(hi) << 16);
}

// ================= W pre-pack: lane-linear bf16 B fragments =================
// frag f = kt*8+nt; lane l provides B[kt*32+(l>>4)*8+j][nt*16+(l&15)], j=0..7.
__global__ __launch_bounds__(256) void pack_w(
    const float* __restrict__ W1, const float* __restrict__ W2,
    uint4* __restrict__ pack)
{
    int e = blockIdx.x * 256 + threadIdx.x;      // 0..4095
    const float* W = (e & 2048) ? W2 : W1;
    int f = (e >> 6) & 31, l = e & 63;
    int kt = f >> 3, nt = f & 7;
    int k0 = kt * 32 + (l >> 4) * 8;
    int col = nt * 16 + (l & 15);
    unsigned int v[8];
#pragma unroll
    for (int j = 0; j < 8; ++j) v[j] = f2bf(W[(size_t)(k0 + j) * D + col]);
    uint4 o;
    o.x = v[0] | (v[1] << 16);
    o.y = v[2] | (v[3] << 16);
    o.z = v[4] | (v[5] << 16);
    o.w = v[6] | (v[7] << 16);
    pack[e] = o;
}

// ================= MFMA GEMM: out = act(X @ W + b) =================
// Block: 256 thr = 4 waves, 128 rows. LDS: x tile 32KB (XOR-swizzled 16B
// chunks) + packed W frags 32KB.
template <bool IN_BF16, bool RELU, bool OUT_BF16>
__global__ __launch_bounds__(256) void gemm_mfma(
    const void* __restrict__ xin, const uint4* __restrict__ wpack,
    const float* __restrict__ b, void* __restrict__ xout, int n_rows)
{
    __shared__ uint4 xs4[2048];
    __shared__ uint4 ws4[2048];
    const int t = threadIdx.x;
    const int row0 = blockIdx.x * 128;

#pragma unroll
    for (int i = 0; i < 8; ++i) ws4[t + 256 * i] = wpack[t + 256 * i];

    if (IN_BF16) {
        const uint4* g = (const uint4*)xin;
#pragma unroll
        for (int i = 0; i < 8; ++i) {
            int c = t + 256 * i;
            int row = c >> 4, kc = c & 15;
            int grow = row0 + row;
            if (grow < n_rows)
                xs4[row * 16 + (kc ^ (row & 7))] = g[(size_t)grow * 16 + kc];
        }
    } else {
        const float4* g = (const float4*)xin;
#pragma unroll
        for (int i = 0; i < 8; ++i) {
            int c = t + 256 * i;
            int row = c >> 4, kc = c & 15;
            int grow = row0 + row;
            if (grow < n_rows) {
                float4 f0 = g[(size_t)grow * 32 + kc * 2];
                float4 f1 = g[(size_t)grow * 32 + kc * 2 + 1];
                uint4 v;
                v.x = pack2(f0.x, f0.y);
                v.y = pack2(f0.z, f0.w);
                v.z = pack2(f1.x, f1.y);
                v.w = pack2(f1.z, f1.w);
                xs4[row * 16 + (kc ^ (row & 7))] = v;
            }
        }
    }
    __syncthreads();

    const int l = t & 63;
    const int w = t >> 6;
    const int l15 = l & 15;
    const int lk = l >> 4;

    float bias_v[8];
#pragma unroll
    for (int nt = 0; nt < 8; ++nt) bias_v[nt] = b[nt * 16 + l15];

    f32x4 acc[2][8];
#pragma unroll
    for (int rt = 0; rt < 2; ++rt)
#pragma unroll
        for (int nt = 0; nt < 8; ++nt) acc[rt][nt] = (f32x4){0.f, 0.f, 0.f, 0.f};

    const int arow0 = w * 32 + l15;
    const int arow1 = arow0 + 16;

#pragma unroll
    for (int kt = 0; kt < 4; ++kt) {
        int kc0 = kt * 4 + lk;
        short8x a0 = *(const short8x*)&xs4[arow0 * 16 + (kc0 ^ (arow0 & 7))];
        short8x a1 = *(const short8x*)&xs4[arow1 * 16 + (kc0 ^ (arow1 & 7))];
#pragma unroll
        for (int nt = 0; nt < 8; ++nt) {
            short8x bf = *(const short8x*)&ws4[(kt * 8 + nt) * 64 + l];
            acc[0][nt] = __builtin_amdgcn_mfma_f32_16x16x32_bf16(a0, bf, acc[0][nt], 0, 0, 0);
            acc[1][nt] = __builtin_amdgcn_mfma_f32_16x16x32_bf16(a1, bf, acc[1][nt], 0, 0, 0);
        }
    }

    // D layout: col = l&15, row = (l>>4)*4 + reg   [m89-verified]
#pragma unroll
    for (int rt = 0; rt < 2; ++rt) {
#pragma unroll
        for (int r = 0; r < 4; ++r) {
            int row = row0 + w * 32 + rt * 16 + lk * 4 + r;
            if (row >= n_rows) continue;
#pragma unroll
            for (int nt = 0; nt < 8; ++nt) {
                float v = acc[rt][nt][r] + bias_v[nt];
                if (RELU) v = fmaxf(v, 0.f);
                int col = nt * 16 + l15;
                if (OUT_BF16)
                    ((unsigned short*)xout)[(size_t)row * D + col] = (unsigned short)f2bf(v);
                else
                    ((float*)xout)[(size_t)row * D + col] = v;
            }
        }
    }
}

// ================= linked-list build =================
// Coalesced per-edge write; only random traffic is atomicExch into 400KB head.
__global__ __launch_bounds__(256) void fill_ll(
    const int* __restrict__ esrc, const int* __restrict__ edst,
    int* __restrict__ head, uint2* __restrict__ nextsrc, int E)
{
    int e = blockIdx.x * 256 + threadIdx.x;
    if (e >= E) return;
    int d = edst[e];
    int s = esrc[e];
    int old = atomicExch(&head[d], e);
    nextsrc[e] = make_uint2((unsigned)old, (unsigned)s);
}

// ================= pull via chain walk =================
// 32 lanes per node (lane -> 4 cols), 8 nodes per 256-thread block.
// nextsrc[e] load is wave-uniform per group (broadcast); h2 row gather is the
// coalesced 256B read that dominates.
__global__ __launch_bounds__(256) void pull_ll(
    const uint2* __restrict__ h2, const int* __restrict__ head,
    const uint2* __restrict__ nextsrc, uint2* __restrict__ agg2, int n_nodes)
{
    int node = blockIdx.x * 8 + (threadIdx.x >> 5);
    int lane = threadIdx.x & 31;
    if (node >= n_nodes) return;
    int e = head[node];
    float a0 = 0.f, a1 = 0.f, a2 = 0.f, a3 = 0.f;
    while (e >= 0) {
        uint2 ns = nextsrc[e];
        uint2 v = h2[(size_t)ns.y * 32 + lane];
        a0 += bflo(v.x); a1 += bfhi(v.x);
        a2 += bflo(v.y); a3 += bfhi(v.y);
        e = (int)ns.x;
    }
    agg2[(size_t)node * 32 + lane] = make_uint2(pack2(a0, a1), pack2(a2, a3));
}

// ================= fallback path (f32 atomic scatter) =================
template <bool RELU>
__global__ __launch_bounds__(256) void gemm_bias_act(
    const float* xin, const float* __restrict__ W,
    const float* __restrict__ b, float* xout, int n_rows)
{
    __shared__ float Ws[D * D];
    __shared__ float xs[32 * D];
    const int t = threadIdx.x;
    const int row0 = blockIdx.x * 32;
    const float4* Wv = (const float4*)W;
    float4* Wsv = (float4*)Ws;
#pragma unroll
    for (int i = 0; i < 16; ++i) Wsv[t + 256 * i] = Wv[t + 256 * i];
    const float4* xv = (const float4*)xin;
    float4* xsv = (float4*)xs;
#pragma unroll
    for (int i = 0; i < 4; ++i) {
        int f4 = t + 256 * i;
        int row = row0 + (f4 >> 5);
        if (row < n_rows) xsv[f4] = xv[(size_t)row0 * 32 + f4];
    }
    __syncthreads();
    const int cg = t & 31;
    const int rg = t >> 5;
    float4 bias = ((const float4*)b)[cg];
    float4 acc[4];
#pragma unroll
    for (int ri = 0; ri < 4; ++ri) acc[ri] = make_float4(0.f, 0.f, 0.f, 0.f);
#pragma unroll 4
    for (int k = 0; k < D; k += 4) {
        float4 w0 = Wsv[(k + 0) * 32 + cg];
        float4 w1 = Wsv[(k + 1) * 32 + cg];
        float4 w2 = Wsv[(k + 2) * 32 + cg];
        float4 w3 = Wsv[(k + 3) * 32 + cg];
#pragma unroll
        for (int ri = 0; ri < 4; ++ri) {
            float4 xa = xsv[(rg + 8 * ri) * 32 + (k >> 2)];
            acc[ri].x = fmaf(xa.x, w0.x, fmaf(xa.y, w1.x, fmaf(xa.z, w2.x, fmaf(xa.w, w3.x, acc[ri].x))));
            acc[ri].y = fmaf(xa.x, w0.y, fmaf(xa.y, w1.y, fmaf(xa.z, w2.y, fmaf(xa.w, w3.y, acc[ri].y))));
            acc[ri].z = fmaf(xa.x, w0.z, fmaf(xa.y, w1.z, fmaf(xa.z, w2.z, fmaf(xa.w, w3.z, acc[ri].z))));
            acc[ri].w = fmaf(xa.x, w0.w, fmaf(xa.y, w1.w, fmaf(xa.z, w2.w, fmaf(xa.w, w3.w, acc[ri].w))));
        }
    }
#pragma unroll
    for (int ri = 0; ri < 4; ++ri) {
        int row = row0 + rg + 8 * ri;
        if (row >= n_rows) continue;
        float4 o;
        o.x = acc[ri].x + bias.x; o.y = acc[ri].y + bias.y;
        o.z = acc[ri].z + bias.z; o.w = acc[ri].w + bias.w;
        if (RELU) {
            o.x = fmaxf(o.x, 0.f); o.y = fmaxf(o.y, 0.f);
            o.z = fmaxf(o.z, 0.f); o.w = fmaxf(o.w, 0.f);
        }
        ((float4*)xout)[(size_t)row * 32 + cg] = o;
    }
}

__global__ __launch_bounds__(256) void zero_kernel(float4* p, int n4)
{
    int i = blockIdx.x * 256 + threadIdx.x;
    int stride = gridDim.x * 256;
    for (; i < n4; i += stride) p[i] = make_float4(0.f, 0.f, 0.f, 0.f);
}

__global__ __launch_bounds__(256) void scatter_kernel(
    const float* __restrict__ h, const int* __restrict__ esrc,
    const int* __restrict__ edst, float* __restrict__ agg, long n_items)
{
    long idx = (long)blockIdx.x * 256 + threadIdx.x;
    long stride = (long)gridDim.x * 256;
    for (; idx < n_items; idx += stride) {
        int e = (int)(idx >> 7);
        int c = (int)(idx & 127);
        int s = esrc[e];
        int d = edst[e];
        unsafeAtomicAdd(&agg[(size_t)d * D + c], h[(size_t)s * D + c]);
    }
}

extern "C" void kernel_launch(void* const* d_in, const int* in_sizes, int n_in,
                              void* d_out, int out_size, void* d_ws, size_t ws_size,
                              hipStream_t stream)
{
    const float* x    = (const float*)d_in[0];
    const int*   esrc = (const int*)d_in[1];
    const int*   edst = (const int*)d_in[2];
    const float* W1   = (const float*)d_in[3];
    const float* b1   = (const float*)d_in[4];
    const float* W2   = (const float*)d_in[5];
    const float* b2   = (const float*)d_in[6];
    float* out = (float*)d_out;

    const int N = in_sizes[0] / D;   // 100000
    const int E = in_sizes[1];       // 1600000

    char* ws = (char*)d_ws;
    size_t off_h    = 0;
    size_t off_agg  = off_h + (size_t)N * 256;          // h2: 25.6 MB
    size_t off_next = off_agg + (size_t)N * 256;        // agg2: 25.6 MB
    size_t off_head = off_next + (size_t)E * 8;         // nextsrc: 12.8 MB
    size_t off_pack = (off_head + (size_t)N * 4 + 255) & ~(size_t)255;
    size_t need     = off_pack + 65536;

    const int nblk = (N + 127) / 128;   // 782

    if (ws_size >= need) {
        uint2* h2      = (uint2*)(ws + off_h);
        uint2* agg2    = (uint2*)(ws + off_agg);
        uint2* nextsrc = (uint2*)(ws + off_next);
        int*   head    = (int*)(ws + off_head);
        uint4* pack    = (uint4*)(ws + off_pack);

        // head = -1
        hipMemsetAsync(head, 0xFF, (size_t)N * 4, stream);

        // 0) pack W1,W2 into lane-linear bf16 B-fragments
        pack_w<<<16, 256, 0, stream>>>(W1, W2, pack);

        // 1) per-dst linked list: coalesced nextsrc write, atomics on 400KB
        fill_ll<<<(E + 255) / 256, 256, 0, stream>>>(esrc, edst, head, nextsrc, E);

        // 2) h = relu(x @ W1 + b1), bf16 out
        gemm_mfma<false, true, true><<<nblk, 256, 0, stream>>>(x, pack, b1, h2, N);

        // 3) agg = chain-walk pull-sum (bf16)
        pull_ll<<<(N + 7) / 8, 256, 0, stream>>>(h2, head, nextsrc, agg2, N);

        // 4) out = agg @ W2 + b2, f32 out
        gemm_mfma<true, false, false><<<nblk, 256, 0, stream>>>(agg2, pack + 2048, b2, out, N);
    } else {
        float* h = (float*)ws;
        const int nb32 = (N + 31) / 32;
        gemm_bias_act<true><<<nb32, 256, 0, stream>>>(x, W1, b1, h, N);
        zero_kernel<<<2048, 256, 0, stream>>>((float4*)out, N * D / 4);
        scatter_kernel<<<8192, 256, 0, stream>>>(h, esrc, edst, out, (long)E * D);
        gemm_bias_act<false><<<nb32, 256, 0, stream>>>(out, W2, b2, out, N);
    }
}